// Round 2
// baseline (206.599 us; speedup 1.0000x reference)
//
#include <hip/hip_runtime.h>
#include <stdint.h>

typedef unsigned short u16;
typedef _Float16 half8 __attribute__((ext_vector_type(8)));
typedef float    f32x4 __attribute__((ext_vector_type(4)));

#define NN 4096
#define SCALE_S 1.2011224087f   // sqrt(log2 e): applied to kq once -> logits in log2 domain

__device__ __forceinline__ u16 f2h(float f) {
    _Float16 h = (_Float16)f;
    return __builtin_bit_cast(u16, h);
}
__device__ __forceinline__ unsigned int pk(u16 a, u16 b) {
    return (unsigned int)a | ((unsigned int)b << 16);
}
__device__ __forceinline__ uint2 pk4h(float a, float b, float c, float d) {
    uint2 r;
    r.x = __builtin_bit_cast(unsigned int, __builtin_amdgcn_cvt_pkrtz(a, b));
    r.y = __builtin_bit_cast(unsigned int, __builtin_amdgcn_cvt_pkrtz(c, d));
    return r;
}
__device__ __forceinline__ void dma16(const u16* src, const u16* dst) {
    __builtin_amdgcn_global_load_lds(
        (const __attribute__((address_space(1))) uint32_t*)src,
        (__attribute__((address_space(3))) uint32_t*)dst, 16, 0, 0);
}

// chunk16 layout for M[d][p] (d = K-dim, inner-8): el = (p>>4)*(2*D) + (d>>3)*128 + (p&15)*8 + (d&7)

// ---------------------------------------------------------------------------
// Kernel 0: weights fp32 -> fp16 chunk16. wA=[w_kq;w_v] [256 m][256 c]; wo [256][128].
// ---------------------------------------------------------------------------
__global__ __launch_bounds__(256) void wcast_kernel(
    const float* __restrict__ wkq, const float* __restrict__ wv,
    const float* __restrict__ wo, u16* __restrict__ wA, u16* __restrict__ woh)
{
    const int gid = blockIdx.x * 256 + threadIdx.x;   // 12288 total
    if (gid < 8192) {
        const int m = gid >> 5, co = gid & 31;
        const float* src = (m < 128) ? &wkq[m * 256 + co * 8] : &wv[(m - 128) * 256 + co * 8];
        u16 h[8];
#pragma unroll
        for (int i = 0; i < 8; ++i) h[i] = f2h(src[i]);
        *(uint4*)(wA + (m >> 4) * 4096 + co * 128 + (m & 15) * 8) =
            make_uint4(pk(h[0],h[1]), pk(h[2],h[3]), pk(h[4],h[5]), pk(h[6],h[7]));
    } else {
        const int u = gid - 8192;
        const int m = u >> 4, co = u & 15;
        const float* src = &wo[m * 128 + co * 8];
        u16 h[8];
#pragma unroll
        for (int i = 0; i < 8; ++i) h[i] = f2h(src[i]);
        *(uint4*)(woh + (m >> 4) * 2048 + co * 128 + (m & 15) * 8) =
            make_uint4(pk(h[0],h[1]), pk(h[2],h[3]), pk(h[4],h[5]), pk(h[6],h[7]));
    }
}

// ---------------------------------------------------------------------------
// Kernel 1: [kq ; v] = wA @ x + bias. M=256 x N=64 pos, K=256 over 4 iters.
// ---------------------------------------------------------------------------
__global__ __launch_bounds__(512, 4) void kqv_kernel(
    const float* __restrict__ x, const u16* __restrict__ wA,
    const float* __restrict__ bkq, const float* __restrict__ bv,
    u16* __restrict__ kqh, u16* __restrict__ vsw)
{
    // u16: A [0,16384) Bpack [16384,20480) ; fp32 scratch at byte 40960: 64 rows x 68
    __shared__ __align__(16) u16 lds[29184];
    float* scr = (float*)&lds[20480];
    const int b  = blockIdx.x & 7;
    const int nb = blockIdx.x >> 3;
    const int n0 = nb << 6;
    const int t  = threadIdx.x;
    const int wave = t >> 6, lane = t & 63;
    const int qq = lane >> 4, c_l = lane & 15;

    f32x4 acc[8];
#pragma unroll
    for (int j = 0; j < 8; ++j) acc[j] = (f32x4){0.f, 0.f, 0.f, 0.f};

    for (int ki = 0; ki < 4; ++ki) {
        __syncthreads();                       // prev MFMA reads done
#pragma unroll
        for (int ch = 0; ch < 4; ++ch) {
            const int c = wave * 4 + ch;
            dma16(wA + (c >> 1) * 4096 + ki * 1024 + (c & 1) * 512 + lane * 8,
                  &lds[c * 512]);
        }
        {
            const int row = t >> 3, seg = t & 7;
            const float* xp = x + (size_t)((b * 256 + ki * 64 + row) * NN) + n0 + seg * 8;
            const float4 xa = *(const float4*)xp;
            const float4 xb = *(const float4*)(xp + 4);
            *(float4*)&scr[row * 68 + seg * 8]     = xa;
            *(float4*)&scr[row * 68 + seg * 8 + 4] = xb;
        }
        __syncthreads();                       // scratch ready, A drained
        {
            const int g = t >> 7, oct = (t >> 4) & 7, p16 = t & 15;
            const int pl = g * 16 + p16;
            float v[8];
#pragma unroll
            for (int i = 0; i < 8; ++i) v[i] = scr[(oct * 8 + i) * 68 + pl];
            const uint2 lo = pk4h(v[0], v[1], v[2], v[3]);
            const uint2 hi = pk4h(v[4], v[5], v[6], v[7]);
            *(uint4*)&lds[16384 + g * 1024 + oct * 128 + p16 * 8] =
                make_uint4(lo.x, lo.y, hi.x, hi.y);
        }
        __syncthreads();                       // Bpack ready

        if (wave < 4) {
#pragma unroll
            for (int ks = 0; ks < 2; ++ks) {
                const half8 a0 = *(const half8*)&lds[(2 * wave) * 1024 + ks * 512 + lane * 8];
                const half8 a1 = *(const half8*)&lds[(2 * wave + 1) * 1024 + ks * 512 + lane * 8];
#pragma unroll
                for (int tn = 0; tn < 4; ++tn) {
                    const half8 bf = *(const half8*)&lds[16384 + tn * 1024 + ks * 512 + lane * 8];
                    acc[tn]     = __builtin_amdgcn_mfma_f32_16x16x32_f16(a0, bf, acc[tn], 0, 0, 0);
                    acc[4 + tn] = __builtin_amdgcn_mfma_f32_16x16x32_f16(a1, bf, acc[4 + tn], 0, 0, 0);
                }
            }
        } else {
            const int w4 = wave - 4;
#pragma unroll
            for (int ks = 0; ks < 2; ++ks) {
                const half8 a0 = *(const half8*)&lds[16384 + w4 * 1024 + ks * 512 + lane * 8];
#pragma unroll
                for (int tn = 0; tn < 8; ++tn) {
                    const half8 bf = *(const half8*)&lds[(8 + tn) * 1024 + ks * 512 + lane * 8];
                    acc[tn] = __builtin_amdgcn_mfma_f32_16x16x32_f16(a0, bf, acc[tn], 0, 0, 0);
                }
            }
        }
    }

    if (wave < 4) {
#pragma unroll
        for (int T = 0; T < 2; ++T) {
            const int m0 = (2 * wave + T) * 16 + qq * 4;
            const float4 bq = *(const float4*)&bkq[m0];
            const int rowoff = ((2 * wave + T) * 2 + (qq >> 1)) * 128 + c_l * 8 + (qq & 1) * 4;
#pragma unroll
            for (int tn = 0; tn < 4; ++tn) {
                const f32x4 a = acc[T * 4 + tn];
                *(uint2*)(kqh + b * 524288 + ((n0 >> 4) + tn) * 2048 + rowoff) =
                    pk4h((a[0] + bq.x) * SCALE_S, (a[1] + bq.y) * SCALE_S,
                         (a[2] + bq.z) * SCALE_S, (a[3] + bq.w) * SCALE_S);
            }
        }
    } else {
        const int w4 = wave - 4;
        const int posq = n0 + w4 * 16 + qq * 4;
#pragma unroll
        for (int tn = 0; tn < 8; ++tn) {
            const float bias = bv[tn * 16 + c_l];
            *(uint2*)(vsw + b * 524288 + tn * 65536 + (posq >> 3) * 128 + c_l * 8 + (posq & 7)) =
                pk4h(acc[tn][0] + bias, acc[tn][1] + bias,
                     acc[tn][2] + bias, acc[tn][3] + bias);
        }
    }
}

// ---------------------------------------------------------------------------
// Kernel 2: flash attention. BM=64, BN=64, D=128. 8 waves = 4 mw x 2 nw
// (512 thr) -> 16 waves/CU (2 blocks) instead of 8: double the TLP at the
// same total work. Each wave: 16 queries x 32 keys. V double-buffered via
// DMA (one barrier/iter); K frags reloaded in-place after QK^T (drained by
// next barrier); P wave-local in LDS; defer-max (THR=8, log2 domain).
// ---------------------------------------------------------------------------
__global__ __launch_bounds__(512, 4) void flash_kernel(
    const u16* __restrict__ kqh, const u16* __restrict__ vsw,
    u16* __restrict__ ctxh)
{
    // u16 idx: V0 [0,8192) V1 [8192,16384) P [16384,20480)   (40 KB)
    __shared__ __align__(16) u16 lds[20480];
    const int b  = blockIdx.x & 7;             // batch -> XCD pinning (keep!)
    const int mt = blockIdx.x >> 3;            // 0..63
    const int t  = threadIdx.x;
    const int wave = t >> 6, lane = t & 63;
    const int qq = lane >> 4, c_l = lane & 15;
    const int mw = wave >> 1, nw = wave & 1;   // mw: query group, nw: key half
    const int pbase = 16384 + wave * 512;
    const u16* kqb = kqh + b * 524288;
    const u16* vb  = vsw + b * 524288;

    // Q B-frags in regs (16 queries x 128 d)
    half8 q[4];
#pragma unroll
    for (int ks = 0; ks < 4; ++ks)
        q[ks] = *(const half8*)(kqb + (mt * 4 + mw) * 2048 + ks * 512 + lane * 8);

    f32x4 o[8];
#pragma unroll
    for (int vt = 0; vt < 8; ++vt) o[vt] = (f32x4){0.f, 0.f, 0.f, 0.f};
    float m_s = -__builtin_inff();
    float l_s = 0.f;

    // prologue: DMA V(0) -> buf0 (16 chunks, 2/wave); K(0) frags -> regs
#pragma unroll
    for (int ch = 0; ch < 2; ++ch) {
        const int cc = wave * 2 + ch;
        dma16(vb + (cc >> 1) * 65536 + (cc & 1) * 512 + lane * 8, &lds[cc * 512]);
    }
    half8 kf[2][4];
#pragma unroll
    for (int nrs = 0; nrs < 2; ++nrs)
#pragma unroll
        for (int ks = 0; ks < 4; ++ks)
            kf[nrs][ks] = *(const half8*)(kqb + (nw * 2 + nrs) * 2048 + ks * 512 + lane * 8);

    for (int it = 0; it < 64; ++it) {
        const int vcur = (it & 1) << 13;       // u16 idx 0 or 8192
        __syncthreads();                       // V(it) staged, K(it) in regs
        if (it < 63) {
#pragma unroll
            for (int ch = 0; ch < 2; ++ch) {   // DMA V(it+1) -> other buf
                const int cc = wave * 2 + ch;
                dma16(vb + (cc >> 1) * 65536 + (it + 1) * 1024 + (cc & 1) * 512 + lane * 8,
                      &lds[(vcur ^ 8192) + cc * 512]);
            }
        }
        // S^T = K.Q^T  (wave's 32 keys x 16 queries)
        f32x4 s0 = (f32x4){0.f, 0.f, 0.f, 0.f};
        f32x4 s1 = (f32x4){0.f, 0.f, 0.f, 0.f};
        __builtin_amdgcn_s_setprio(1);
#pragma unroll
        for (int ks = 0; ks < 4; ++ks) {
            s0 = __builtin_amdgcn_mfma_f32_16x16x32_f16(kf[0][ks], q[ks], s0, 0, 0, 0);
            s1 = __builtin_amdgcn_mfma_f32_16x16x32_f16(kf[1][ks], q[ks], s1, 0, 0, 0);
        }
        __builtin_amdgcn_s_setprio(0);
        // reload K(it+1) into the same regs (WAR orders after QK^T; the
        // vmcnt(0) at the next barrier guarantees arrival)
        if (it < 63) {
#pragma unroll
            for (int nrs = 0; nrs < 2; ++nrs)
#pragma unroll
                for (int ks = 0; ks < 4; ++ks)
                    kf[nrs][ks] = *(const half8*)(kqb + ((it + 1) * 4 + nw * 2 + nrs) * 2048 + ks * 512 + lane * 8);
        }

        // online softmax (base-2) with defer-max; lane state = query col c_l
        float mx = fmaxf(fmaxf(fmaxf(s0[0], s0[1]), fmaxf(s0[2], s0[3])),
                         fmaxf(fmaxf(s1[0], s1[1]), fmaxf(s1[2], s1[3])));
        mx = fmaxf(mx, __shfl_xor(mx, 16, 64));
        mx = fmaxf(mx, __shfl_xor(mx, 32, 64));
        const int up = mx > m_s + 8.f;
        const float mn = up ? mx : m_s;
        const float al = __builtin_amdgcn_exp2f(m_s - mn);   // ==1 when deferred
        m_s = mn;
        const float p0 = __builtin_amdgcn_exp2f(s0[0] - mn);
        const float p1 = __builtin_amdgcn_exp2f(s0[1] - mn);
        const float p2 = __builtin_amdgcn_exp2f(s0[2] - mn);
        const float p3 = __builtin_amdgcn_exp2f(s0[3] - mn);
        const float p4 = __builtin_amdgcn_exp2f(s1[0] - mn);
        const float p5 = __builtin_amdgcn_exp2f(s1[1] - mn);
        const float p6 = __builtin_amdgcn_exp2f(s1[2] - mn);
        const float p7 = __builtin_amdgcn_exp2f(s1[3] - mn);
        const float ps = ((p0 + p1) + (p2 + p3)) + ((p4 + p5) + (p6 + p7));
        *(uint2*)&lds[pbase + (qq >> 1) * 128 + c_l * 8 + (qq & 1) * 4]       = pk4h(p0, p1, p2, p3);
        *(uint2*)&lds[pbase + (2 + (qq >> 1)) * 128 + c_l * 8 + (qq & 1) * 4] = pk4h(p4, p5, p6, p7);
        l_s = l_s * al + ps;
        if (__any(up)) {
#pragma unroll
            for (int vt = 0; vt < 8; ++vt) o[vt] *= al;
        }

        // O += P V  (P wave-local: in-order DS within wave, no barrier)
        const half8 pf = *(const half8*)&lds[pbase + lane * 8];
        __builtin_amdgcn_s_setprio(1);
#pragma unroll
        for (int vt = 0; vt < 8; ++vt) {
            const half8 vf = *(const half8*)&lds[vcur + vt * 1024 + nw * 512 + lane * 8];
            o[vt] = __builtin_amdgcn_mfma_f32_16x16x32_f16(vf, pf, o[vt], 0, 0, 0);
        }
        __builtin_amdgcn_s_setprio(0);
    }

    // ---- epilogue: merge the nw pair per mw group ----
    l_s += __shfl_xor(l_s, 16, 64);
    l_s += __shfl_xor(l_s, 32, 64);
    __syncthreads();
    float* mlf = (float*)&lds[16384];          // P region reuse (1 KB used)
    if (qq == 0) {
        mlf[wave * 32 + c_l * 2]     = m_s;
        mlf[wave * 32 + c_l * 2 + 1] = l_s;
    }
    __syncthreads();
    const int pslot = (mw * 2 + (nw ^ 1)) * 32 + c_l * 2;
    const float m2 = mlf[pslot], l2 = mlf[pslot + 1];
    const float ms = fmaxf(m_s, m2);
    const float ga = __builtin_amdgcn_exp2f(m_s - ms);
    const float g2 = __builtin_amdgcn_exp2f(m2 - ms);
    const float inv = 1.f / (l_s * ga + l2 * g2);
    __syncthreads();
    float* obuf = (float*)lds;                 // V region reuse (32 KB)
    if (nw == 1) {
#pragma unroll
        for (int vt = 0; vt < 8; ++vt)
            *(f32x4*)&obuf[mw * 2048 + (vt * 64 + lane) * 4] = o[vt] * ga;
    }
    __syncthreads();
    if (nw == 0) {
        u16* cb = ctxh + b * 524288;
#pragma unroll
        for (int vt = 0; vt < 8; ++vt) {
            const f32x4 op = *(const f32x4*)&obuf[mw * 2048 + (vt * 64 + lane) * 4];
            const f32x4 oo = (o[vt] * ga + op) * inv;
            *(uint2*)(cb + (mt * 4 + mw) * 2048 + (vt * 2 + (qq >> 1)) * 128 +
                      c_l * 8 + (qq & 1) * 4) = pk4h(oo[0], oo[1], oo[2], oo[3]);
        }
    }
}

// ---------------------------------------------------------------------------
// Kernel 3: out = w_o @ ctx + b_o (fp32). M=256 x N=64, K=128. Grid 512.
// ---------------------------------------------------------------------------
__global__ __launch_bounds__(512, 4) void out_kernel(
    const u16* __restrict__ woh, const u16* __restrict__ ctxh,
    const float* __restrict__ bo, float* __restrict__ out)
{
    __shared__ __align__(16) u16 lds[20480];   // A(wo) 16384 | B(ctx) 4096
    const int b  = blockIdx.x & 7;
    const int nb = blockIdx.x >> 3;
    const int n0 = nb << 6;
    const int t  = threadIdx.x;
    const int wave = t >> 6, lane = t & 63;
    const int qq = lane >> 4, c_l = lane & 15;

    f32x4 acc[2][4];
#pragma unroll
    for (int i = 0; i < 2; ++i)
#pragma unroll
        for (int j = 0; j < 4; ++j) acc[i][j] = (f32x4){0.f, 0.f, 0.f, 0.f};

    for (int ki = 0; ki < 2; ++ki) {
        __syncthreads();
#pragma unroll
        for (int ch = 0; ch < 5; ++ch) {
            const int c = wave * 5 + ch;               // 0..39
            if (c < 32) {
                dma16(woh + (c >> 1) * 2048 + ki * 1024 + (c & 1) * 512 + lane * 8,
                      &lds[c * 512]);
            } else {
                const int cc = c - 32;                 // 0..7
                dma16(ctxh + b * 524288 + ((n0 >> 4) + (cc >> 1)) * 2048 + ki * 1024 +
                          (cc & 1) * 512 + lane * 8,
                      &lds[16384 + cc * 512]);
            }
        }
        __syncthreads();
#pragma unroll
        for (int ks = 0; ks < 2; ++ks) {
            const half8 a0 = *(const half8*)&lds[(2 * wave) * 1024 + ks * 512 + lane * 8];
            const half8 a1 = *(const half8*)&lds[(2 * wave + 1) * 1024 + ks * 512 + lane * 8];
#pragma unroll
            for (int tn = 0; tn < 4; ++tn) {
                const half8 bf = *(const half8*)&lds[16384 + tn * 1024 + ks * 512 + lane * 8];
                acc[0][tn] = __builtin_amdgcn_mfma_f32_16x16x32_f16(a0, bf, acc[0][tn], 0, 0, 0);
                acc[1][tn] = __builtin_amdgcn_mfma_f32_16x16x32_f16(a1, bf, acc[1][tn], 0, 0, 0);
            }
        }
    }

#pragma unroll
    for (int T = 0; T < 2; ++T) {
        const int m0 = (2 * wave + T) * 16 + qq * 4;
        const float4 bq = *(const float4*)&bo[m0];
#pragma unroll
        for (int tn = 0; tn < 4; ++tn) {
            const int pos = n0 + tn * 16 + c_l;
            out[(size_t)((b * 256 + m0 + 0) * NN) + pos] = acc[T][tn][0] + bq.x;
            out[(size_t)((b * 256 + m0 + 1) * NN) + pos] = acc[T][tn][1] + bq.y;
            out[(size_t)((b * 256 + m0 + 2) * NN) + pos] = acc[T][tn][2] + bq.z;
            out[(size_t)((b * 256 + m0 + 3) * NN) + pos] = acc[T][tn][3] + bq.w;
        }
    }
}

// ---------------------------------------------------------------------------
extern "C" void kernel_launch(void* const* d_in, const int* in_sizes, int n_in,
                              void* d_out, int out_size, void* d_ws, size_t ws_size,
                              hipStream_t stream) {
    const float* x    = (const float*)d_in[0];
    const float* w_kq = (const float*)d_in[1];
    const float* b_kq = (const float*)d_in[2];
    const float* w_v  = (const float*)d_in[3];
    const float* b_v  = (const float*)d_in[4];
    const float* w_o  = (const float*)d_in[5];
    const float* b_o  = (const float*)d_in[6];
    float* out = (float*)d_out;

    u16* kqh  = (u16*)d_ws;
    u16* vsw  = (u16*)((char*)d_ws + (8u << 20));
    u16* ctxh = (u16*)((char*)d_ws + (16u << 20));
    u16* wA   = (u16*)((char*)d_ws + (24u << 20));
    u16* woh  = wA + 65536;

    wcast_kernel<<<dim3(48), dim3(256), 0, stream>>>(w_kq, w_v, w_o, wA, woh);
    kqv_kernel<<<dim3(512), dim3(512), 0, stream>>>(x, wA, b_kq, b_v, kqh, vsw);
    flash_kernel<<<dim3(512), dim3(512), 0, stream>>>(kqh, vsw, ctxh);
    out_kernel<<<dim3(512), dim3(512), 0, stream>>>(woh, ctxh, b_o, out);
}

// Round 3
// 190.094 us; speedup vs baseline: 1.0868x; 1.0868x over previous
//
#include <hip/hip_runtime.h>
#include <stdint.h>

typedef unsigned short u16;
typedef _Float16 half8 __attribute__((ext_vector_type(8)));
typedef float    f32x4 __attribute__((ext_vector_type(4)));
typedef float    f32x16 __attribute__((ext_vector_type(16)));

#define NN 4096
#define SCALE_S 1.2011224087f   // sqrt(log2 e): applied to kq once -> logits in log2 domain

__device__ __forceinline__ u16 f2h(float f) {
    _Float16 h = (_Float16)f;
    return __builtin_bit_cast(u16, h);
}
__device__ __forceinline__ unsigned int pk(u16 a, u16 b) {
    return (unsigned int)a | ((unsigned int)b << 16);
}
__device__ __forceinline__ unsigned int pkr(float a, float b) {
    return __builtin_bit_cast(unsigned int, __builtin_amdgcn_cvt_pkrtz(a, b));
}
__device__ __forceinline__ uint2 pk4h(float a, float b, float c, float d) {
    uint2 r;
    r.x = pkr(a, b);
    r.y = pkr(c, d);
    return r;
}
__device__ __forceinline__ void dma16(const u16* src, const u16* dst) {
    __builtin_amdgcn_global_load_lds(
        (const __attribute__((address_space(1))) uint32_t*)src,
        (__attribute__((address_space(3))) uint32_t*)dst, 16, 0, 0);
}

// ---------------------------------------------------------------------------
// Layouts (all per batch, f16):
//  kqh (K and Q, 128 d x 4096 pos), A/B frag for 32x32x16 MFMA:
//    el(d,p) = (p>>5)*4096 + (d>>4)*512 + ((d&15)>>3)*256 + (p&31)*8 + (d&7)
//    -> lane l reads chunk + l*8: row/col = p = blk*32+(l&31), k = (l>>5)*8+j
//  vsw (V, 128 vchan x 4096 pos), A-frag rows=vchan, k=key with the key
//  PERMUTATION pi(s) absorbed into storage (pi swaps key bits 2<->3 within
//  each 16-group) so P packs straight from QK^T C-regs into the B-operand:
//    el(v,p) = (p>>4)*2048 + (v>>5)*512 + ((p>>2)&1)*256 + (v&31)*8 + ((p>>3)&1)*4 + (p&3)
//  ctxh: chunk16 (unchanged, consumed by out_kernel):
//    el(v,p) = (p>>4)*2048 + (v>>3)*128 + (p&15)*8 + (v&7)
// ---------------------------------------------------------------------------

// ---------------------------------------------------------------------------
// Kernel 0: weights fp32 -> fp16 chunk16. wA=[w_kq;w_v] [256 m][256 c]; wo [256][128].
// ---------------------------------------------------------------------------
__global__ __launch_bounds__(256) void wcast_kernel(
    const float* __restrict__ wkq, const float* __restrict__ wv,
    const float* __restrict__ wo, u16* __restrict__ wA, u16* __restrict__ woh)
{
    const int gid = blockIdx.x * 256 + threadIdx.x;   // 12288 total
    if (gid < 8192) {
        const int m = gid >> 5, co = gid & 31;
        const float* src = (m < 128) ? &wkq[m * 256 + co * 8] : &wv[(m - 128) * 256 + co * 8];
        u16 h[8];
#pragma unroll
        for (int i = 0; i < 8; ++i) h[i] = f2h(src[i]);
        *(uint4*)(wA + (m >> 4) * 4096 + co * 128 + (m & 15) * 8) =
            make_uint4(pk(h[0],h[1]), pk(h[2],h[3]), pk(h[4],h[5]), pk(h[6],h[7]));
    } else {
        const int u = gid - 8192;
        const int m = u >> 4, co = u & 15;
        const float* src = &wo[m * 128 + co * 8];
        u16 h[8];
#pragma unroll
        for (int i = 0; i < 8; ++i) h[i] = f2h(src[i]);
        *(uint4*)(woh + (m >> 4) * 2048 + co * 128 + (m & 15) * 8) =
            make_uint4(pk(h[0],h[1]), pk(h[2],h[3]), pk(h[4],h[5]), pk(h[6],h[7]));
    }
}

// ---------------------------------------------------------------------------
// Kernel 1: [kq ; v] = wA @ x + bias. M=256 x N=64 pos, K=256 over 4 iters.
// Same GEMM core as before; only the write-out layouts changed (see header).
// ---------------------------------------------------------------------------
__global__ __launch_bounds__(512, 4) void kqv_kernel(
    const float* __restrict__ x, const u16* __restrict__ wA,
    const float* __restrict__ bkq, const float* __restrict__ bv,
    u16* __restrict__ kqh, u16* __restrict__ vsw)
{
    // u16: A [0,16384) Bpack [16384,20480) ; fp32 scratch at byte 40960: 64 rows x 68
    __shared__ __align__(16) u16 lds[29184];
    float* scr = (float*)&lds[20480];
    const int b  = blockIdx.x & 7;
    const int nb = blockIdx.x >> 3;
    const int n0 = nb << 6;
    const int t  = threadIdx.x;
    const int wave = t >> 6, lane = t & 63;
    const int qq = lane >> 4, c_l = lane & 15;

    f32x4 acc[8];
#pragma unroll
    for (int j = 0; j < 8; ++j) acc[j] = (f32x4){0.f, 0.f, 0.f, 0.f};

    for (int ki = 0; ki < 4; ++ki) {
        __syncthreads();                       // prev MFMA reads done
#pragma unroll
        for (int ch = 0; ch < 4; ++ch) {
            const int c = wave * 4 + ch;
            dma16(wA + (c >> 1) * 4096 + ki * 1024 + (c & 1) * 512 + lane * 8,
                  &lds[c * 512]);
        }
        {
            const int row = t >> 3, seg = t & 7;
            const float* xp = x + (size_t)((b * 256 + ki * 64 + row) * NN) + n0 + seg * 8;
            const float4 xa = *(const float4*)xp;
            const float4 xb = *(const float4*)(xp + 4);
            *(float4*)&scr[row * 68 + seg * 8]     = xa;
            *(float4*)&scr[row * 68 + seg * 8 + 4] = xb;
        }
        __syncthreads();                       // scratch ready, A drained
        {
            const int g = t >> 7, oct = (t >> 4) & 7, p16 = t & 15;
            const int pl = g * 16 + p16;
            float v[8];
#pragma unroll
            for (int i = 0; i < 8; ++i) v[i] = scr[(oct * 8 + i) * 68 + pl];
            const uint2 lo = pk4h(v[0], v[1], v[2], v[3]);
            const uint2 hi = pk4h(v[4], v[5], v[6], v[7]);
            *(uint4*)&lds[16384 + g * 1024 + oct * 128 + p16 * 8] =
                make_uint4(lo.x, lo.y, hi.x, hi.y);
        }
        __syncthreads();                       // Bpack ready

        if (wave < 4) {
#pragma unroll
            for (int ks = 0; ks < 2; ++ks) {
                const half8 a0 = *(const half8*)&lds[(2 * wave) * 1024 + ks * 512 + lane * 8];
                const half8 a1 = *(const half8*)&lds[(2 * wave + 1) * 1024 + ks * 512 + lane * 8];
#pragma unroll
                for (int tn = 0; tn < 4; ++tn) {
                    const half8 bf = *(const half8*)&lds[16384 + tn * 1024 + ks * 512 + lane * 8];
                    acc[tn]     = __builtin_amdgcn_mfma_f32_16x16x32_f16(a0, bf, acc[tn], 0, 0, 0);
                    acc[4 + tn] = __builtin_amdgcn_mfma_f32_16x16x32_f16(a1, bf, acc[4 + tn], 0, 0, 0);
                }
            }
        } else {
            const int w4 = wave - 4;
#pragma unroll
            for (int ks = 0; ks < 2; ++ks) {
                const half8 a0 = *(const half8*)&lds[16384 + w4 * 1024 + ks * 512 + lane * 8];
#pragma unroll
                for (int tn = 0; tn < 8; ++tn) {
                    const half8 bf = *(const half8*)&lds[(8 + tn) * 1024 + ks * 512 + lane * 8];
                    acc[tn] = __builtin_amdgcn_mfma_f32_16x16x32_f16(a0, bf, acc[tn], 0, 0, 0);
                }
            }
        }
    }

    if (wave < 4) {
        // kq rows: acc[T*4+tn] = kq[d = (2w+T)*16+qq*4+r][pos = n0+tn*16+c_l]
#pragma unroll
        for (int T = 0; T < 2; ++T) {
            const int m0 = (2 * wave + T) * 16 + qq * 4;
            const float4 bq = *(const float4*)&bkq[m0];
            const int base = b * 524288 + (n0 >> 5) * 4096 + (2 * wave + T) * 512 +
                             (qq >> 1) * 256 + c_l * 8 + (qq & 1) * 4;
#pragma unroll
            for (int tn = 0; tn < 4; ++tn) {
                const f32x4 a = acc[T * 4 + tn];
                *(uint2*)(kqh + base + (tn >> 1) * 4096 + (tn & 1) * 128) =
                    pk4h((a[0] + bq.x) * SCALE_S, (a[1] + bq.y) * SCALE_S,
                         (a[2] + bq.z) * SCALE_S, (a[3] + bq.w) * SCALE_S);
            }
        }
    } else {
        // v rows: acc[tn] = v[vchan = tn*16+c_l][pos = n0+w4*16+qq*4+r]
        const int w4 = wave - 4;
        const int base = b * 524288 + ((n0 >> 4) + w4) * 2048 + (qq & 1) * 256 +
                         c_l * 8 + (qq >> 1) * 4;
#pragma unroll
        for (int tn = 0; tn < 8; ++tn) {
            const float bias = bv[tn * 16 + c_l];
            *(uint2*)(vsw + base + (tn >> 1) * 512 + (tn & 1) * 128) =
                pk4h(acc[tn][0] + bias, acc[tn][1] + bias,
                     acc[tn][2] + bias, acc[tn][3] + bias);
        }
    }
}

// ---------------------------------------------------------------------------
// Kernel 2: flash attention, 32x32x16 MFMA, swapped QK^T (S^T = K.Q^T so each
// lane owns one query column: softmax is 15 in-lane fmax + 1 shfl). P packs
// straight from C-regs into the PV B-operand via cvt_pkrtz (the k-slot/key
// permutation is absorbed into vsw's storage layout) -- NO LDS for P, no
// cross-lane exchange. 4 waves = 2 qt x 2 nw, BM=64 q, 128 keys/iter, 32
// iters. V double-buffered via DMA; K frags in regs reloaded in place.
// ---------------------------------------------------------------------------
__global__ __launch_bounds__(256, 2) void flash_kernel(
    const u16* __restrict__ kqh, const u16* __restrict__ vsw,
    u16* __restrict__ ctxh)
{
    // u16: V0 [0,16384) V1 [16384,32768). Epilogue reuse: obuf f32 at 0,
    // m/l exchange f32 at u16 idx 16384.
    __shared__ __align__(16) u16 lds[32768];
    const int b  = blockIdx.x & 7;             // batch -> XCD pinning
    const int mt = blockIdx.x >> 3;            // 0..63 (64-query tile)
    const int t  = threadIdx.x;
    const int wave = t >> 6, lane = t & 63;
    const int h = lane >> 5, c = lane & 31;    // C-frag: col(query)=c, row-half=h
    const int qt = wave >> 1, nw = wave & 1;   // qt: 32-query group, nw: key half
    const u16* kqb = kqh + b * 524288;
    const u16* vb  = vsw + b * 524288;

    // Q B-frags (32 queries x 128 d): col=query, k=(l>>5)*8+j
    half8 qf[8];
#pragma unroll
    for (int dc = 0; dc < 8; ++dc)
        qf[dc] = *(const half8*)(kqb + (mt * 2 + qt) * 4096 + dc * 512 + lane * 8);

    f32x16 o[4];
#pragma unroll
    for (int vt = 0; vt < 4; ++vt)
#pragma unroll
        for (int r = 0; r < 16; ++r) o[vt][r] = 0.f;
    float m_s = -__builtin_inff();
    float l_s = 0.f;

    // prologue: DMA V(0) (32 KB = 32 chunks, 8/wave); K(0) A-frags -> regs
#pragma unroll
    for (int ch = 0; ch < 8; ++ch) {
        const int cc = wave * 8 + ch;
        dma16(vb + cc * 512 + lane * 8, &lds[cc * 512]);
    }
    half8 kf[2][8];
#pragma unroll
    for (int kb = 0; kb < 2; ++kb)
#pragma unroll
        for (int dc = 0; dc < 8; ++dc)
            kf[kb][dc] = *(const half8*)(kqb + (nw * 2 + kb) * 4096 + dc * 512 + lane * 8);

    for (int it = 0; it < 32; ++it) {
        const int vcur = (it & 1) << 14;       // u16 idx 0 or 16384
        __syncthreads();                       // V(it) staged, K(it) in regs
        if (it < 31) {
#pragma unroll
            for (int ch = 0; ch < 8; ++ch) {   // DMA V(it+1) -> other buf
                const int cc = wave * 8 + ch;
                dma16(vb + (it + 1) * 16384 + cc * 512 + lane * 8,
                      &lds[(vcur ^ 16384) + cc * 512]);
            }
        }
        const int vbase = vcur + nw * 8192;

#pragma unroll
        for (int kb = 0; kb < 2; ++kb) {
            // S^T(32 keys x 32 queries) over D=128: 8 chained MFMAs
            f32x16 s;
#pragma unroll
            for (int r = 0; r < 16; ++r) s[r] = 0.f;
#pragma unroll
            for (int dc = 0; dc < 8; ++dc)
                s = __builtin_amdgcn_mfma_f32_32x32x16_f16(kf[kb][dc], qf[dc], s, 0, 0, 0);
            // reload this kb's K frags for it+1 (WAR after QK^T; next
            // barrier's vmcnt(0) guarantees arrival)
            if (it < 31) {
                const u16* kp = kqb + ((it + 1) * 4 + nw * 2 + kb) * 4096;
#pragma unroll
                for (int dc = 0; dc < 8; ++dc)
                    kf[kb][dc] = *(const half8*)(kp + dc * 512 + lane * 8);
            }

            // online softmax (base-2, defer-max THR=8); lane owns query c,
            // 16 of the 32 keys (partner lane l^32 owns the other 16)
            float mx = fmaxf(
                fmaxf(fmaxf(fmaxf(s[0], s[1]), fmaxf(s[2], s[3])),
                      fmaxf(fmaxf(s[4], s[5]), fmaxf(s[6], s[7]))),
                fmaxf(fmaxf(fmaxf(s[8], s[9]), fmaxf(s[10], s[11])),
                      fmaxf(fmaxf(s[12], s[13]), fmaxf(s[14], s[15]))));
            mx = fmaxf(mx, __shfl_xor(mx, 32, 64));
            const int up = mx > m_s + 8.f;
            const float mn = up ? mx : m_s;
            const float al = __builtin_amdgcn_exp2f(m_s - mn);   // ==1 when deferred
            m_s = mn;
            float p[16];
#pragma unroll
            for (int r = 0; r < 16; ++r) p[r] = __builtin_amdgcn_exp2f(s[r] - mn);
            const float ps = (((p[0] + p[1]) + (p[2] + p[3])) + ((p[4] + p[5]) + (p[6] + p[7])))
                           + (((p[8] + p[9]) + (p[10] + p[11])) + ((p[12] + p[13]) + (p[14] + p[15])));
            l_s = l_s * al + ps;
            if (__any(up)) {
#pragma unroll
                for (int vt = 0; vt < 4; ++vt) o[vt] *= al;
            }

            // pack P into PV B-operands (k-slot permutation absorbed in vsw)
            uint4 w0, w1;
            w0.x = pkr(p[0], p[1]);  w0.y = pkr(p[2], p[3]);
            w0.z = pkr(p[4], p[5]);  w0.w = pkr(p[6], p[7]);
            w1.x = pkr(p[8], p[9]);  w1.y = pkr(p[10], p[11]);
            w1.z = pkr(p[12], p[13]); w1.w = pkr(p[14], p[15]);
            const half8 bf0 = __builtin_bit_cast(half8, w0);
            const half8 bf1 = __builtin_bit_cast(half8, w1);

            // O += V.P  (V A-frags from LDS; keys kc*16.. within kb)
            const int v0 = vbase + kb * 4096;
#pragma unroll
            for (int vt = 0; vt < 4; ++vt) {
                const half8 vf = *(const half8*)&lds[v0 + vt * 512 + lane * 8];
                o[vt] = __builtin_amdgcn_mfma_f32_32x32x16_f16(vf, bf0, o[vt], 0, 0, 0);
            }
#pragma unroll
            for (int vt = 0; vt < 4; ++vt) {
                const half8 vf = *(const half8*)&lds[v0 + 2048 + vt * 512 + lane * 8];
                o[vt] = __builtin_amdgcn_mfma_f32_32x32x16_f16(vf, bf1, o[vt], 0, 0, 0);
            }
        }
    }

    // ---- epilogue ----
    // merge l across the h pair (disjoint key subsets, same m by construction)
    l_s += __shfl_xor(l_s, 32, 64);
    __syncthreads();                           // all V reads done; LDS reusable
    float* mlf = (float*)&lds[16384];          // 256 floats
    if (h == 0) {
        mlf[wave * 64 + c * 2]     = m_s;
        mlf[wave * 64 + c * 2 + 1] = l_s;
    }
    __syncthreads();
    const int pslot = (qt * 2 + (nw ^ 1)) * 64 + c * 2;
    const float m2 = mlf[pslot], l2 = mlf[pslot + 1];
    const float ms = fmaxf(m_s, m2);
    const float g  = __builtin_amdgcn_exp2f(m_s - ms);
    const float g2 = __builtin_amdgcn_exp2f(m2 - ms);
    const float inv = 1.f / (l_s * g + l2 * g2);
    float* obuf = (float*)lds;                 // 32 KB (disjoint from mlf)
    if (nw == 1) {
#pragma unroll
        for (int vt = 0; vt < 4; ++vt)
#pragma unroll
            for (int rg = 0; rg < 4; ++rg) {
                f32x4 ov;
                ov[0] = o[vt][rg * 4 + 0] * g; ov[1] = o[vt][rg * 4 + 1] * g;
                ov[2] = o[vt][rg * 4 + 2] * g; ov[3] = o[vt][rg * 4 + 3] * g;
                *(f32x4*)&obuf[qt * 4096 + (vt * 4 + rg) * 256 + lane * 4] = ov;
            }
    }
    __syncthreads();
    if (nw == 0) {
        u16* cb = ctxh + b * 524288;
        const int pbase = (mt * 4 + qt * 2 + (c >> 4)) * 2048 + (c & 15) * 8 + h * 4;
#pragma unroll
        for (int vt = 0; vt < 4; ++vt)
#pragma unroll
            for (int rg = 0; rg < 4; ++rg) {
                const f32x4 op = *(const f32x4*)&obuf[qt * 4096 + (vt * 4 + rg) * 256 + lane * 4];
                const float o0 = (o[vt][rg * 4 + 0] * g + op[0]) * inv;
                const float o1 = (o[vt][rg * 4 + 1] * g + op[1]) * inv;
                const float o2 = (o[vt][rg * 4 + 2] * g + op[2]) * inv;
                const float o3 = (o[vt][rg * 4 + 3] * g + op[3]) * inv;
                *(uint2*)(cb + pbase + (vt * 4 + rg) * 128) = pk4h(o0, o1, o2, o3);
            }
    }
}

// ---------------------------------------------------------------------------
// Kernel 3: out = w_o @ ctx + b_o (fp32). M=256 x N=64, K=128. Grid 512.
// ---------------------------------------------------------------------------
__global__ __launch_bounds__(512, 4) void out_kernel(
    const u16* __restrict__ woh, const u16* __restrict__ ctxh,
    const float* __restrict__ bo, float* __restrict__ out)
{
    __shared__ __align__(16) u16 lds[20480];   // A(wo) 16384 | B(ctx) 4096
    const int b  = blockIdx.x & 7;
    const int nb = blockIdx.x >> 3;
    const int n0 = nb << 6;
    const int t  = threadIdx.x;
    const int wave = t >> 6, lane = t & 63;
    const int qq = lane >> 4, c_l = lane & 15;

    f32x4 acc[2][4];
#pragma unroll
    for (int i = 0; i < 2; ++i)
#pragma unroll
        for (int j = 0; j < 4; ++j) acc[i][j] = (f32x4){0.f, 0.f, 0.f, 0.f};

    for (int ki = 0; ki < 2; ++ki) {
        __syncthreads();
#pragma unroll
        for (int ch = 0; ch < 5; ++ch) {
            const int c = wave * 5 + ch;               // 0..39
            if (c < 32) {
                dma16(woh + (c >> 1) * 2048 + ki * 1024 + (c & 1) * 512 + lane * 8,
                      &lds[c * 512]);
            } else {
                const int cc = c - 32;                 // 0..7
                dma16(ctxh + b * 524288 + ((n0 >> 4) + (cc >> 1)) * 2048 + ki * 1024 +
                          (cc & 1) * 512 + lane * 8,
                      &lds[16384 + cc * 512]);
            }
        }
        __syncthreads();
#pragma unroll
        for (int ks = 0; ks < 2; ++ks) {
            const half8 a0 = *(const half8*)&lds[(2 * wave) * 1024 + ks * 512 + lane * 8];
            const half8 a1 = *(const half8*)&lds[(2 * wave + 1) * 1024 + ks * 512 + lane * 8];
#pragma unroll
            for (int tn = 0; tn < 4; ++tn) {
                const half8 bf = *(const half8*)&lds[16384 + tn * 1024 + ks * 512 + lane * 8];
                acc[0][tn] = __builtin_amdgcn_mfma_f32_16x16x32_f16(a0, bf, acc[0][tn], 0, 0, 0);
                acc[1][tn] = __builtin_amdgcn_mfma_f32_16x16x32_f16(a1, bf, acc[1][tn], 0, 0, 0);
            }
        }
    }

#pragma unroll
    for (int T = 0; T < 2; ++T) {
        const int m0 = (2 * wave + T) * 16 + qq * 4;
        const float4 bq = *(const float4*)&bo[m0];
#pragma unroll
        for (int tn = 0; tn < 4; ++tn) {
            const int pos = n0 + tn * 16 + c_l;
            out[(size_t)((b * 256 + m0 + 0) * NN) + pos] = acc[T][tn][0] + bq.x;
            out[(size_t)((b * 256 + m0 + 1) * NN) + pos] = acc[T][tn][1] + bq.y;
            out[(size_t)((b * 256 + m0 + 2) * NN) + pos] = acc[T][tn][2] + bq.z;
            out[(size_t)((b * 256 + m0 + 3) * NN) + pos] = acc[T][tn][3] + bq.w;
        }
    }
}

// ---------------------------------------------------------------------------
extern "C" void kernel_launch(void* const* d_in, const int* in_sizes, int n_in,
                              void* d_out, int out_size, void* d_ws, size_t ws_size,
                              hipStream_t stream) {
    const float* x    = (const float*)d_in[0];
    const float* w_kq = (const float*)d_in[1];
    const float* b_kq = (const float*)d_in[2];
    const float* w_v  = (const float*)d_in[3];
    const float* b_v  = (const float*)d_in[4];
    const float* w_o  = (const float*)d_in[5];
    const float* b_o  = (const float*)d_in[6];
    float* out = (float*)d_out;

    u16* kqh  = (u16*)d_ws;
    u16* vsw  = (u16*)((char*)d_ws + (8u << 20));
    u16* ctxh = (u16*)((char*)d_ws + (16u << 20));
    u16* wA   = (u16*)((char*)d_ws + (24u << 20));
    u16* woh  = wA + 65536;

    wcast_kernel<<<dim3(48), dim3(256), 0, stream>>>(w_kq, w_v, w_o, wA, woh);
    kqv_kernel<<<dim3(512), dim3(512), 0, stream>>>(x, wA, b_kq, b_v, kqh, vsw);
    flash_kernel<<<dim3(512), dim3(256), 0, stream>>>(kqh, vsw, ctxh);
    out_kernel<<<dim3(512), dim3(512), 0, stream>>>(woh, ctxh, b_o, out);
}

// Round 4
// 189.045 us; speedup vs baseline: 1.0929x; 1.0056x over previous
//
#include <hip/hip_runtime.h>
#include <stdint.h>

typedef unsigned short u16;
typedef _Float16 half8 __attribute__((ext_vector_type(8)));
typedef float    f32x4 __attribute__((ext_vector_type(4)));
typedef float    f32x16 __attribute__((ext_vector_type(16)));

#define NN 4096
#define SCALE_S 1.2011224087f   // sqrt(log2 e): applied to kq once -> logits in log2 domain

__device__ __forceinline__ u16 f2h(float f) {
    _Float16 h = (_Float16)f;
    return __builtin_bit_cast(u16, h);
}
__device__ __forceinline__ unsigned int pk(u16 a, u16 b) {
    return (unsigned int)a | ((unsigned int)b << 16);
}
__device__ __forceinline__ unsigned int pkr(float a, float b) {
    return __builtin_bit_cast(unsigned int, __builtin_amdgcn_cvt_pkrtz(a, b));
}
__device__ __forceinline__ uint2 pk4h(float a, float b, float c, float d) {
    uint2 r;
    r.x = pkr(a, b);
    r.y = pkr(c, d);
    return r;
}
__device__ __forceinline__ void dma16(const u16* src, const u16* dst) {
    __builtin_amdgcn_global_load_lds(
        (const __attribute__((address_space(1))) uint32_t*)src,
        (__attribute__((address_space(3))) uint32_t*)dst, 16, 0, 0);
}

// ---------------------------------------------------------------------------
// Layouts (all per batch, f16). 32-chunk scheme for 32x32x16 MFMA operands:
//    el(d,p) = (p>>5)*4096 + (d>>4)*512 + ((d&15)>>3)*256 + (p&31)*8 + (d&7)
//    -> lane l reads chunk + l*8: row/col = p = blk*32+(l&31), k = (l>>5)*8+j
//  kqh (K and Q, 128 d x 4096 pos): 32-chunk scheme above.
//  vsw (V, 128 vchan x 4096 pos), A-frag rows=vchan, k=key with the key
//  PERMUTATION absorbed into storage so P packs straight from QK^T C-regs
//  into the PV B-operand:
//    el(v,p) = (p>>4)*2048 + (v>>5)*512 + ((p>>2)&1)*256 + (v&31)*8 + ((p>>3)&1)*4 + (p&3)
//  woh (w_o, 256 co x 128 v): 32-chunk scheme, row = co, k = v:
//    el(co,v) = (co>>5)*4096 + (v>>4)*512 + ((v>>3)&1)*256 + (co&31)*8 + (v&7)
//  out_kernel is FUSED into flash's epilogue (ctx never leaves the block).
// ---------------------------------------------------------------------------

// ---------------------------------------------------------------------------
// Kernel 0: weights fp32 -> fp16. wA=[w_kq;w_v] [256 m][256 c] chunk16 (for
// kqv's 16x16x32 MFMAs); wo [256 co][128 v] in 32-chunk scheme (for fused out).
// ---------------------------------------------------------------------------
__global__ __launch_bounds__(256) void wcast_kernel(
    const float* __restrict__ wkq, const float* __restrict__ wv,
    const float* __restrict__ wo, u16* __restrict__ wA, u16* __restrict__ woh)
{
    const int gid = blockIdx.x * 256 + threadIdx.x;   // 12288 total
    if (gid < 8192) {
        const int m = gid >> 5, co = gid & 31;
        const float* src = (m < 128) ? &wkq[m * 256 + co * 8] : &wv[(m - 128) * 256 + co * 8];
        u16 h[8];
#pragma unroll
        for (int i = 0; i < 8; ++i) h[i] = f2h(src[i]);
        *(uint4*)(wA + (m >> 4) * 4096 + co * 128 + (m & 15) * 8) =
            make_uint4(pk(h[0],h[1]), pk(h[2],h[3]), pk(h[4],h[5]), pk(h[6],h[7]));
    } else {
        const int u = gid - 8192;
        const int m = u >> 4, co8 = u & 15;    // m = out channel co, v base = co8*8
        const float* src = &wo[m * 128 + co8 * 8];
        u16 h[8];
#pragma unroll
        for (int i = 0; i < 8; ++i) h[i] = f2h(src[i]);
        *(uint4*)(woh + (m >> 5) * 4096 + (co8 >> 1) * 512 + (co8 & 1) * 256 + (m & 31) * 8) =
            make_uint4(pk(h[0],h[1]), pk(h[2],h[3]), pk(h[4],h[5]), pk(h[6],h[7]));
    }
}

// ---------------------------------------------------------------------------
// Kernel 1: [kq ; v] = wA @ x + bias. M=256 x N=64 pos, K=256 over 4 iters.
// ---------------------------------------------------------------------------
__global__ __launch_bounds__(512, 4) void kqv_kernel(
    const float* __restrict__ x, const u16* __restrict__ wA,
    const float* __restrict__ bkq, const float* __restrict__ bv,
    u16* __restrict__ kqh, u16* __restrict__ vsw)
{
    // u16: A [0,16384) Bpack [16384,20480) ; fp32 scratch at byte 40960: 64 rows x 68
    __shared__ __align__(16) u16 lds[29184];
    float* scr = (float*)&lds[20480];
    const int b  = blockIdx.x & 7;
    const int nb = blockIdx.x >> 3;
    const int n0 = nb << 6;
    const int t  = threadIdx.x;
    const int wave = t >> 6, lane = t & 63;
    const int qq = lane >> 4, c_l = lane & 15;

    f32x4 acc[8];
#pragma unroll
    for (int j = 0; j < 8; ++j) acc[j] = (f32x4){0.f, 0.f, 0.f, 0.f};

    for (int ki = 0; ki < 4; ++ki) {
        __syncthreads();                       // prev MFMA reads done
#pragma unroll
        for (int ch = 0; ch < 4; ++ch) {
            const int c = wave * 4 + ch;
            dma16(wA + (c >> 1) * 4096 + ki * 1024 + (c & 1) * 512 + lane * 8,
                  &lds[c * 512]);
        }
        {
            const int row = t >> 3, seg = t & 7;
            const float* xp = x + (size_t)((b * 256 + ki * 64 + row) * NN) + n0 + seg * 8;
            const float4 xa = *(const float4*)xp;
            const float4 xb = *(const float4*)(xp + 4);
            *(float4*)&scr[row * 68 + seg * 8]     = xa;
            *(float4*)&scr[row * 68 + seg * 8 + 4] = xb;
        }
        __syncthreads();                       // scratch ready, A drained
        {
            const int g = t >> 7, oct = (t >> 4) & 7, p16 = t & 15;
            const int pl = g * 16 + p16;
            float v[8];
#pragma unroll
            for (int i = 0; i < 8; ++i) v[i] = scr[(oct * 8 + i) * 68 + pl];
            const uint2 lo = pk4h(v[0], v[1], v[2], v[3]);
            const uint2 hi = pk4h(v[4], v[5], v[6], v[7]);
            *(uint4*)&lds[16384 + g * 1024 + oct * 128 + p16 * 8] =
                make_uint4(lo.x, lo.y, hi.x, hi.y);
        }
        __syncthreads();                       // Bpack ready

        if (wave < 4) {
#pragma unroll
            for (int ks = 0; ks < 2; ++ks) {
                const half8 a0 = *(const half8*)&lds[(2 * wave) * 1024 + ks * 512 + lane * 8];
                const half8 a1 = *(const half8*)&lds[(2 * wave + 1) * 1024 + ks * 512 + lane * 8];
#pragma unroll
                for (int tn = 0; tn < 4; ++tn) {
                    const half8 bf = *(const half8*)&lds[16384 + tn * 1024 + ks * 512 + lane * 8];
                    acc[tn]     = __builtin_amdgcn_mfma_f32_16x16x32_f16(a0, bf, acc[tn], 0, 0, 0);
                    acc[4 + tn] = __builtin_amdgcn_mfma_f32_16x16x32_f16(a1, bf, acc[4 + tn], 0, 0, 0);
                }
            }
        } else {
            const int w4 = wave - 4;
#pragma unroll
            for (int ks = 0; ks < 2; ++ks) {
                const half8 a0 = *(const half8*)&lds[16384 + w4 * 1024 + ks * 512 + lane * 8];
#pragma unroll
                for (int tn = 0; tn < 8; ++tn) {
                    const half8 bf = *(const half8*)&lds[(8 + tn) * 1024 + ks * 512 + lane * 8];
                    acc[tn] = __builtin_amdgcn_mfma_f32_16x16x32_f16(a0, bf, acc[tn], 0, 0, 0);
                }
            }
        }
    }

    if (wave < 4) {
        // kq rows: acc[T*4+tn] = kq[d = (2w+T)*16+qq*4+r][pos = n0+tn*16+c_l]
#pragma unroll
        for (int T = 0; T < 2; ++T) {
            const int m0 = (2 * wave + T) * 16 + qq * 4;
            const float4 bq = *(const float4*)&bkq[m0];
            const int base = b * 524288 + (n0 >> 5) * 4096 + (2 * wave + T) * 512 +
                             (qq >> 1) * 256 + c_l * 8 + (qq & 1) * 4;
#pragma unroll
            for (int tn = 0; tn < 4; ++tn) {
                const f32x4 a = acc[T * 4 + tn];
                *(uint2*)(kqh + base + (tn >> 1) * 4096 + (tn & 1) * 128) =
                    pk4h((a[0] + bq.x) * SCALE_S, (a[1] + bq.y) * SCALE_S,
                         (a[2] + bq.z) * SCALE_S, (a[3] + bq.w) * SCALE_S);
            }
        }
    } else {
        // v rows: acc[tn] = v[vchan = tn*16+c_l][pos = n0+w4*16+qq*4+r]
        const int w4 = wave - 4;
        const int base = b * 524288 + ((n0 >> 4) + w4) * 2048 + (qq & 1) * 256 +
                         c_l * 8 + (qq >> 1) * 4;
#pragma unroll
        for (int tn = 0; tn < 8; ++tn) {
            const float bias = bv[tn * 16 + c_l];
            *(uint2*)(vsw + base + (tn >> 1) * 512 + (tn & 1) * 128) =
                pk4h(acc[tn][0] + bias, acc[tn][1] + bias,
                     acc[tn][2] + bias, acc[tn][3] + bias);
        }
    }
}

// ---------------------------------------------------------------------------
// Kernel 2: flash attention + FUSED output projection.
// 32x32x16 MFMA, swapped QK^T (lane owns one query: softmax in-lane), P packs
// from C-regs into PV B-operand (key permutation absorbed in vsw layout).
// 4 waves = 2 qt x 2 nw, BM=64 q, 128 keys/iter, 32 iters. V dbuf via DMA;
// K frags in regs reloaded in place. Epilogue: ctx -> LDS (16 KB, 32-chunk
// scheme), then all 4 waves compute out = w_o @ ctx + b_o and store fp32.
// ---------------------------------------------------------------------------
__global__ __launch_bounds__(256, 2) void flash_kernel(
    const u16* __restrict__ kqh, const u16* __restrict__ vsw,
    const u16* __restrict__ woh, const float* __restrict__ bo,
    float* __restrict__ out)
{
    // u16: V0 [0,16384) V1 [16384,32768).
    // Epilogue reuse (post-barrier): obuf f32 [0,16384); mlf f32 @16384 (1KB);
    // ctxf f16 @18432 (16 KB, 32-chunk scheme).
    __shared__ __align__(16) u16 lds[32768];
    const int b  = blockIdx.x & 7;             // batch -> XCD pinning
    const int mt = blockIdx.x >> 3;            // 0..63 (64-query tile)
    const int t  = threadIdx.x;
    const int wave = t >> 6, lane = t & 63;
    const int h = lane >> 5, c = lane & 31;    // C-frag: col(query)=c, row-half=h
    const int qt = wave >> 1, nw = wave & 1;   // qt: 32-query group, nw: key half
    const u16* kqb = kqh + b * 524288;
    const u16* vb  = vsw + b * 524288;

    // Q B-frags (32 queries x 128 d): col=query, k=(l>>5)*8+j
    half8 qf[8];
#pragma unroll
    for (int dc = 0; dc < 8; ++dc)
        qf[dc] = *(const half8*)(kqb + (mt * 2 + qt) * 4096 + dc * 512 + lane * 8);

    f32x16 o[4];
#pragma unroll
    for (int vt = 0; vt < 4; ++vt)
#pragma unroll
        for (int r = 0; r < 16; ++r) o[vt][r] = 0.f;
    float m_s = -__builtin_inff();
    float l_s = 0.f;

    // prologue: DMA V(0) (32 KB = 32 chunks, 8/wave); K(0) A-frags -> regs
#pragma unroll
    for (int ch = 0; ch < 8; ++ch) {
        const int cc = wave * 8 + ch;
        dma16(vb + cc * 512 + lane * 8, &lds[cc * 512]);
    }
    half8 kf[2][8];
#pragma unroll
    for (int kb = 0; kb < 2; ++kb)
#pragma unroll
        for (int dc = 0; dc < 8; ++dc)
            kf[kb][dc] = *(const half8*)(kqb + (nw * 2 + kb) * 4096 + dc * 512 + lane * 8);

    for (int it = 0; it < 32; ++it) {
        const int vcur = (it & 1) << 14;       // u16 idx 0 or 16384
        __syncthreads();                       // V(it) staged, K(it) in regs
        if (it < 31) {
#pragma unroll
            for (int ch = 0; ch < 8; ++ch) {   // DMA V(it+1) -> other buf
                const int cc = wave * 8 + ch;
                dma16(vb + (it + 1) * 16384 + cc * 512 + lane * 8,
                      &lds[(vcur ^ 16384) + cc * 512]);
            }
        }
        const int vbase = vcur + nw * 8192;

#pragma unroll
        for (int kb = 0; kb < 2; ++kb) {
            // S^T(32 keys x 32 queries) over D=128: 8 chained MFMAs
            f32x16 s;
#pragma unroll
            for (int r = 0; r < 16; ++r) s[r] = 0.f;
            __builtin_amdgcn_s_setprio(1);
#pragma unroll
            for (int dc = 0; dc < 8; ++dc)
                s = __builtin_amdgcn_mfma_f32_32x32x16_f16(kf[kb][dc], qf[dc], s, 0, 0, 0);
            __builtin_amdgcn_s_setprio(0);
            // reload this kb's K frags for it+1 (WAR after QK^T; next
            // barrier's vmcnt(0) guarantees arrival)
            if (it < 31) {
                const u16* kp = kqb + ((it + 1) * 4 + nw * 2 + kb) * 4096;
#pragma unroll
                for (int dc = 0; dc < 8; ++dc)
                    kf[kb][dc] = *(const half8*)(kp + dc * 512 + lane * 8);
            }

            // online softmax (base-2, defer-max THR=8); lane owns query c,
            // 16 of the 32 keys (partner lane l^32 owns the other 16)
            float mx = fmaxf(
                fmaxf(fmaxf(fmaxf(s[0], s[1]), fmaxf(s[2], s[3])),
                      fmaxf(fmaxf(s[4], s[5]), fmaxf(s[6], s[7]))),
                fmaxf(fmaxf(fmaxf(s[8], s[9]), fmaxf(s[10], s[11])),
                      fmaxf(fmaxf(s[12], s[13]), fmaxf(s[14], s[15]))));
            mx = fmaxf(mx, __shfl_xor(mx, 32, 64));
            const int up = mx > m_s + 8.f;
            const float mn = up ? mx : m_s;
            const float al = __builtin_amdgcn_exp2f(m_s - mn);   // ==1 when deferred
            m_s = mn;
            float p[16];
#pragma unroll
            for (int r = 0; r < 16; ++r) p[r] = __builtin_amdgcn_exp2f(s[r] - mn);
            const float ps = (((p[0] + p[1]) + (p[2] + p[3])) + ((p[4] + p[5]) + (p[6] + p[7])))
                           + (((p[8] + p[9]) + (p[10] + p[11])) + ((p[12] + p[13]) + (p[14] + p[15])));
            l_s = l_s * al + ps;
            if (__any(up)) {
#pragma unroll
                for (int vt = 0; vt < 4; ++vt) o[vt] *= al;
            }

            // pack P into PV B-operands (k-slot permutation absorbed in vsw)
            uint4 w0, w1;
            w0.x = pkr(p[0], p[1]);  w0.y = pkr(p[2], p[3]);
            w0.z = pkr(p[4], p[5]);  w0.w = pkr(p[6], p[7]);
            w1.x = pkr(p[8], p[9]);  w1.y = pkr(p[10], p[11]);
            w1.z = pkr(p[12], p[13]); w1.w = pkr(p[14], p[15]);
            const half8 bf0 = __builtin_bit_cast(half8, w0);
            const half8 bf1 = __builtin_bit_cast(half8, w1);

            // O += V.P  (V A-frags from LDS)
            const int v0 = vbase + kb * 4096;
            __builtin_amdgcn_s_setprio(1);
#pragma unroll
            for (int vt = 0; vt < 4; ++vt) {
                const half8 vf = *(const half8*)&lds[v0 + vt * 512 + lane * 8];
                o[vt] = __builtin_amdgcn_mfma_f32_32x32x16_f16(vf, bf0, o[vt], 0, 0, 0);
            }
#pragma unroll
            for (int vt = 0; vt < 4; ++vt) {
                const half8 vf = *(const half8*)&lds[v0 + 2048 + vt * 512 + lane * 8];
                o[vt] = __builtin_amdgcn_mfma_f32_32x32x16_f16(vf, bf1, o[vt], 0, 0, 0);
            }
            __builtin_amdgcn_s_setprio(0);
        }
    }

    // ---- epilogue part 1: merge the nw pair, ctx -> LDS ----
    l_s += __shfl_xor(l_s, 32, 64);
    __syncthreads();                           // all V reads done; LDS reusable
    float* mlf = (float*)&lds[16384];          // 256 floats
    if (h == 0) {
        mlf[wave * 64 + c * 2]     = m_s;
        mlf[wave * 64 + c * 2 + 1] = l_s;
    }
    __syncthreads();
    const int pslot = (qt * 2 + (nw ^ 1)) * 64 + c * 2;
    const float m2 = mlf[pslot], l2 = mlf[pslot + 1];
    const float ms = fmaxf(m_s, m2);
    const float g  = __builtin_amdgcn_exp2f(m_s - ms);
    const float g2 = __builtin_amdgcn_exp2f(m2 - ms);
    const float inv = 1.f / (l_s * g + l2 * g2);
    float* obuf = (float*)lds;                 // 32 KB (disjoint from mlf/ctxf)
    if (nw == 1) {
#pragma unroll
        for (int vt = 0; vt < 4; ++vt)
#pragma unroll
            for (int rg = 0; rg < 4; ++rg) {
                f32x4 ov;
                ov[0] = o[vt][rg * 4 + 0] * g; ov[1] = o[vt][rg * 4 + 1] * g;
                ov[2] = o[vt][rg * 4 + 2] * g; ov[3] = o[vt][rg * 4 + 3] * g;
                *(f32x4*)&obuf[qt * 4096 + (vt * 4 + rg) * 256 + lane * 4] = ov;
            }
    }
    __syncthreads();
    if (nw == 0) {
        // ctx[v = vt*32 + rg*8 + 4h + ri][q = qt*32 + c] -> ctxf 32-chunk:
        // addr = qt*4096 + (vt*2 + (rg>>1))*512 + (rg&1)*256 + c*8 + 4h + ri
#pragma unroll
        for (int vt = 0; vt < 4; ++vt)
#pragma unroll
            for (int rg = 0; rg < 4; ++rg) {
                const f32x4 op = *(const f32x4*)&obuf[qt * 4096 + (vt * 4 + rg) * 256 + lane * 4];
                const float o0 = (o[vt][rg * 4 + 0] * g + op[0]) * inv;
                const float o1 = (o[vt][rg * 4 + 1] * g + op[1]) * inv;
                const float o2 = (o[vt][rg * 4 + 2] * g + op[2]) * inv;
                const float o3 = (o[vt][rg * 4 + 3] * g + op[3]) * inv;
                *(uint2*)&lds[18432 + qt * 4096 + (vt * 2 + (rg >> 1)) * 512 +
                              (rg & 1) * 256 + c * 8 + h * 4] = pk4h(o0, o1, o2, o3);
            }
    }

    // ---- epilogue part 2: fused out = w_o @ ctx + b_o ----
    __syncthreads();                           // ctxf ready
#pragma unroll
    for (int cb = 0; cb < 2; ++cb) {
        const int cob = wave * 2 + cb;         // 8 co-blocks over 4 waves
        const u16* wp = woh + cob * 4096;
        half8 af[8];
#pragma unroll
        for (int dc = 0; dc < 8; ++dc)
            af[dc] = *(const half8*)(wp + dc * 512 + lane * 8);
#pragma unroll
        for (int qb = 0; qb < 2; ++qb) {
            f32x16 acc;
#pragma unroll
            for (int r = 0; r < 16; ++r) acc[r] = 0.f;
            __builtin_amdgcn_s_setprio(1);
#pragma unroll
            for (int dc = 0; dc < 8; ++dc) {
                const half8 bfr = *(const half8*)&lds[18432 + qb * 4096 + dc * 512 + lane * 8];
                acc = __builtin_amdgcn_mfma_f32_32x32x16_f16(af[dc], bfr, acc, 0, 0, 0);
            }
            __builtin_amdgcn_s_setprio(0);
            const int pos = mt * 64 + qb * 32 + c;
#pragma unroll
            for (int r = 0; r < 16; ++r) {
                const int co = cob * 32 + (r & 3) + 8 * (r >> 2) + 4 * h;
                out[(size_t)(b * 256 + co) * NN + pos] = acc[r] + bo[co];
            }
        }
    }
}

// ---------------------------------------------------------------------------
extern "C" void kernel_launch(void* const* d_in, const int* in_sizes, int n_in,
                              void* d_out, int out_size, void* d_ws, size_t ws_size,
                              hipStream_t stream) {
    const float* x    = (const float*)d_in[0];
    const float* w_kq = (const float*)d_in[1];
    const float* b_kq = (const float*)d_in[2];
    const float* w_v  = (const float*)d_in[3];
    const float* b_v  = (const float*)d_in[4];
    const float* w_o  = (const float*)d_in[5];
    const float* b_o  = (const float*)d_in[6];
    float* out = (float*)d_out;

    u16* kqh  = (u16*)d_ws;
    u16* vsw  = (u16*)((char*)d_ws + (8u << 20));
    u16* wA   = (u16*)((char*)d_ws + (24u << 20));
    u16* woh  = wA + 65536;

    wcast_kernel<<<dim3(48), dim3(256), 0, stream>>>(w_kq, w_v, w_o, wA, woh);
    kqv_kernel<<<dim3(512), dim3(512), 0, stream>>>(x, wA, b_kq, b_v, kqh, vsw);
    flash_kernel<<<dim3(512), dim3(256), 0, stream>>>(kqh, vsw, woh, b_o, out);
}